// Round 2
// baseline (618.070 us; speedup 1.0000x reference)
//
#include <hip/hip_runtime.h>

#define NFRAMES 3749   // (960000-512)/256 + 1
#define NBLOCKS 3750   // 256-sample hop blocks per batch (960000/256)
#define NSAMP   960000
#define NBATCH  32
#define SORTN   4096
#define NWORDS  59     // ceil(3749/64)
#define SILENCE_FRAMES 18
#define MIN_SPEECH_FRAMES 6

// Kernel A: per 256-sample hop-block sum of fp32 squares, accumulated in fp64.
// One wave (64 lanes) per hop block; each lane loads one float4 (coalesced).
__global__ __launch_bounds__(256) void vad_block_sums(const float* __restrict__ wav,
                                                      double* __restrict__ bs) {
    int wave = (blockIdx.x << 2) + (threadIdx.x >> 6);   // [0, NBATCH*NBLOCKS)
    int lane = threadIdx.x & 63;
    int b = wave / NBLOCKS;
    int h = wave - b * NBLOCKS;
    const float* p = wav + (size_t)b * NSAMP + h * 256 + lane * 4;
    float4 v = *(const float4*)p;
    // square in fp32 (matches reference frames*frames rounding), sum in fp64
    float s0 = v.x * v.x;
    float s1 = v.y * v.y;
    float s2 = v.z * v.z;
    float s3 = v.w * v.w;
    double acc = (double)s0 + (double)s1 + (double)s2 + (double)s3;
    #pragma unroll
    for (int off = 32; off > 0; off >>= 1)
        acc += __shfl_down(acc, off, 64);
    if (lane == 0) bs[wave] = acc;
}

// Kernel B: one block per batch. energies -> sort -> threshold -> mask ->
// serial VAD state machine -> coverage -> int32 output.
__global__ __launch_bounds__(256) void vad_finish(const double* __restrict__ bs,
                                                  int* __restrict__ out) {
    __shared__ float se[SORTN];                 // sort buffer
    __shared__ float eng[NFRAMES];              // energies
    __shared__ unsigned long long mw[64];       // mask bits
    __shared__ unsigned char cov[NFRAMES];      // coverage
    __shared__ float thr_sh;
    __shared__ int nzero_sh;

    int b = blockIdx.x;
    int tid = threadIdx.x;
    const double* row = bs + (size_t)b * NBLOCKS;

    // Phase 1: energies into LDS (exact fp64 sum -> single fp32 rounding)
    for (int t = tid; t < SORTN; t += 256) {
        float e;
        if (t < NFRAMES) {
            double s = row[t] + row[t + 1];
            e = (float)(s * (1.0 / 512.0));
            eng[t] = e;
        } else {
            e = 3.402823466e+38f; // FLT_MAX pad -> sorts to the top
        }
        se[t] = e;
    }

    // Phase 2: bitonic sort ascending, 4096 elements
    for (int k = 2; k <= SORTN; k <<= 1) {
        for (int j = k >> 1; j > 0; j >>= 1) {
            __syncthreads();
            for (int i = tid; i < SORTN; i += 256) {
                int ixj = i ^ j;
                if (ixj > i) {
                    float a = se[i], c = se[ixj];
                    bool up = ((i & k) == 0);
                    if ((a > c) == up) { se[i] = c; se[ixj] = a; }
                }
            }
        }
    }
    __syncthreads();

    // Phase 3: nzero = count of energies <= 0
    if (tid == 0) nzero_sh = 0;
    __syncthreads();
    int cnt = 0;
    for (int i = tid; i < NFRAMES; i += 256) cnt += (se[i] <= 0.0f) ? 1 : 0;
    if (cnt) atomicAdd(&nzero_sh, cnt);
    __syncthreads();

    // Phase 4: threshold (fp32 arithmetic exactly as reference)
    if (tid == 0) {
        int nzero = nzero_sh;
        int nz = NFRAMES - nzero;
        float thr;
        if (nz > 0) {
            float pos = 0.2f * (float)(nz - 1);
            int lo = (int)floorf(pos);
            int hi = (int)ceilf(pos);
            float frac = pos - (float)lo;
            int ilo = min(max(nzero + lo, 0), NFRAMES - 1);
            int ihi = min(max(nzero + hi, 0), NFRAMES - 1);
            thr = se[ilo] * (1.0f - frac) + se[ihi] * frac;
        } else {
            thr = 0.01f;
        }
        thr_sh = thr;
    }
    __syncthreads();
    float thr = thr_sh;

    // Phase 5: mask bits via ballot; init coverage
    int lane = tid & 63, wv = tid >> 6;
    for (int wi = wv; wi < NWORDS; wi += 4) {
        int t = (wi << 6) + lane;
        bool p = (t < NFRAMES) && (eng[t] > thr);
        unsigned long long bm = __ballot(p);
        if (lane == 0) mw[wi] = bm;
    }
    for (int t = tid; t < NFRAMES; t += 256) cov[t] = 0;
    __syncthreads();

    // Phase 6: serial VAD state machine (thread 0)
    if (tid == 0) {
        bool in_sp = false;
        int start = 0, sil = 0;
        unsigned long long w = 0;
        for (int t = 0; t < NFRAMES; ++t) {
            if ((t & 63) == 0) w = mw[t >> 6];
            bool mt = (w >> (t & 63)) & 1ull;
            int start2 = (mt && !in_sp) ? t : start;
            int sil2 = mt ? 0 : (in_sp ? sil + 1 : sil);
            bool closed = (!mt) && in_sp && (sil2 >= SILENCE_FRAMES);
            if (closed) {
                int end = t - sil2;
                if (end - start2 >= MIN_SPEECH_FRAMES)
                    for (int x = start2; x < end; ++x) cov[x] = 1;
                in_sp = false;
            }
            if (mt) in_sp = true;
            start = start2;
            sil = sil2;
        }
        if (in_sp && (NFRAMES - start >= MIN_SPEECH_FRAMES))
            for (int x = start; x < NFRAMES; ++x) cov[x] = 1;
    }
    __syncthreads();

    // Phase 7: write output as int32 0/1 (harness marshals bool output as int32)
    int* orow = out + (size_t)b * NFRAMES;
    for (int t = tid; t < NFRAMES; t += 256) orow[t] = cov[t] ? 1 : 0;
}

extern "C" void kernel_launch(void* const* d_in, const int* in_sizes, int n_in,
                              void* d_out, int out_size, void* d_ws, size_t ws_size,
                              hipStream_t stream) {
    const float* wav = (const float*)d_in[0];
    int* out = (int*)d_out;
    double* bs = (double*)d_ws;   // NBATCH*NBLOCKS doubles = 960 KB

    vad_block_sums<<<(NBATCH * NBLOCKS) / 4, 256, 0, stream>>>(wav, bs);
    vad_finish<<<NBATCH, 256, 0, stream>>>(bs, out);
}

// Round 3
// 206.702 us; speedup vs baseline: 2.9901x; 2.9901x over previous
//
#include <hip/hip_runtime.h>

#define NFRAMES 3749   // (960000-512)/256 + 1
#define NBLOCKS 3750   // 256-sample hop blocks per batch (960000/256)
#define NSAMP   960000
#define NBATCH  32
#define NWORDS  59     // ceil(3750/64) -> covers bit index up to 3775 (incl. e==NFRAMES)
#define SILENCE_FRAMES 18
#define MIN_SPEECH_FRAMES 6
#define MAXSEG  256    // true bound: 1 + floor(3748/19) = 198

// Kernel A: fp64 sums of fp32 squares per 256-sample hop block.
// Block = 4096 samples (16 hop blocks). Thread owns 16 consecutive samples,
// 16-lane butterfly reduce (4 shfl_xor levels) -> one write per hop block.
__global__ __launch_bounds__(256) void vad_block_sums(const float* __restrict__ wav,
                                                      double* __restrict__ bs) {
    int tid = threadIdx.x;
    const float* p = wav + (size_t)blockIdx.x * 4096 + tid * 16;
    double acc = 0.0;
    #pragma unroll
    for (int i = 0; i < 4; ++i) {
        float4 v = *(const float4*)(p + i * 4);
        acc += (double)(v.x * v.x);
        acc += (double)(v.y * v.y);
        acc += (double)(v.z * v.z);
        acc += (double)(v.w * v.w);
    }
    #pragma unroll
    for (int m = 1; m < 16; m <<= 1)
        acc += __shfl_xor(acc, m, 64);
    if ((tid & 15) == 0)
        bs[(size_t)blockIdx.x * 16 + (tid >> 4)] = acc;
}

// Kernel B: one block per batch. energies -> radix-select quantile -> mask bits
// -> parallel segment extraction (windowed bit ops) -> int32 coverage output.
__global__ __launch_bounds__(256) void vad_finish(const double* __restrict__ bs,
                                                  int* __restrict__ out) {
    __shared__ float eng[NFRAMES];
    __shared__ int hist[256], cum[256];
    __shared__ unsigned long long mw[NWORDS];   // mask bits
    __shared__ unsigned long long sw[NWORDS];   // segment-start bits
    __shared__ unsigned long long lw[NWORDS];   // segment-last-one bits
    __shared__ unsigned long long Sw[NWORDS];   // valid-segment start markers
    __shared__ unsigned long long Ew[NWORDS];   // valid-segment end markers
    __shared__ int wbS[NWORDS], wbL[NWORDS];    // word-prefix bit counts
    __shared__ int startpos[MAXSEG], lastpos[MAXSEG];
    __shared__ int nzero_sh, nseg_sh;
    __shared__ int sel_prefix, sel_k;
    __shared__ int ranks[2];
    __shared__ float selval[2];
    __shared__ float thr_sh;

    int b = blockIdx.x;
    int tid = threadIdx.x;
    int lane = tid & 63, wv = tid >> 6;
    const double* row = bs + (size_t)b * NBLOCKS;

    if (tid == 0) nzero_sh = 0;
    __syncthreads();

    // Phase 1: energies (exact fp64 sum -> single fp32 rounding) + nzero count
    int myzero = 0;
    for (int t = tid; t < NFRAMES; t += 256) {
        double s = row[t] + row[t + 1];
        float e = (float)(s * (1.0 / 512.0));
        eng[t] = e;
        if (e <= 0.0f) myzero++;
    }
    if (myzero) atomicAdd(&nzero_sh, myzero);
    __syncthreads();

    // Phase 2: quantile ranks
    if (tid == 0) {
        int nzero = nzero_sh, nz = NFRAMES - nzero;
        if (nz > 0) {
            float pos = 0.2f * (float)(nz - 1);
            int lo = (int)floorf(pos), hi = (int)ceilf(pos);
            ranks[0] = min(max(nzero + lo, 0), NFRAMES - 1);
            ranks[1] = min(max(nzero + hi, 0), NFRAMES - 1);
        } else {
            ranks[0] = -1;
        }
    }
    __syncthreads();

    // Phase 3: radix select (4 byte passes) for each rank.
    // Positive fp32 bit patterns order identically to the floats.
    for (int r = 0; r < 2; ++r) {
        if (ranks[0] < 0) break;                 // block-uniform
        if (tid == 0) { sel_prefix = 0; sel_k = ranks[r]; }
        for (int shift = 24; shift >= 0; shift -= 8) {
            hist[tid] = 0;
            __syncthreads();                     // also orders sel_prefix/sel_k writes
            unsigned pmask = (shift == 24) ? 0u : (0xFFFFFFFFu << (shift + 8));
            unsigned pref = (unsigned)sel_prefix;
            for (int t = tid; t < NFRAMES; t += 256) {
                unsigned u = __float_as_uint(eng[t]);
                if ((u & pmask) == (pref & pmask))
                    atomicAdd(&hist[(u >> shift) & 255], 1);
            }
            __syncthreads();
            cum[tid] = hist[tid];
            __syncthreads();
            for (int off = 1; off < 256; off <<= 1) {
                int v = cum[tid];
                int add = (tid >= off) ? cum[tid - off] : 0;
                __syncthreads();
                cum[tid] = v + add;
                __syncthreads();
            }
            int excl = cum[tid] - hist[tid];
            int kk = sel_k;
            if (hist[tid] > 0 && excl <= kk && kk < cum[tid]) {   // exactly one thread
                sel_prefix = sel_prefix | (tid << shift);
                sel_k = kk - excl;
            }
            __syncthreads();
        }
        if (tid == 0) selval[r] = __uint_as_float((unsigned)sel_prefix);
        __syncthreads();
    }

    // Phase 4: threshold (fp32 arithmetic exactly as reference)
    if (tid == 0) {
        int nzero = nzero_sh, nz = NFRAMES - nzero;
        float thr;
        if (nz > 0) {
            float pos = 0.2f * (float)(nz - 1);
            int lo = (int)floorf(pos);
            float frac = pos - (float)lo;
            thr = selval[0] * (1.0f - frac) + selval[1] * frac;
        } else {
            thr = 0.01f;
        }
        thr_sh = thr;
    }
    __syncthreads();
    float thr = thr_sh;

    // Phase 5: mask bit-words via ballot
    for (int wi = wv; wi < NWORDS; wi += 4) {
        int t = (wi << 6) + lane;
        bool p = (t < NFRAMES) && (eng[t] > thr);
        unsigned long long bm = __ballot(p);
        if (lane == 0) mw[wi] = bm;
    }
    __syncthreads();

    // Phase 6: segment starts (no 1 in prev 18) / last-ones (no 1 in next 18)
    for (int wi = wv; wi < NWORDS; wi += 4) {
        unsigned long long W  = mw[wi];
        unsigned long long Wm = (wi > 0) ? mw[wi - 1] : 0ull;
        unsigned long long Wp = (wi + 1 < NWORDS) ? mw[wi + 1] : 0ull;
        int l = lane;
        bool mt = (W >> l) & 1ull;
        bool prev_any, next_any;
        if (l >= 18) {
            prev_any = ((W >> (l - 18)) & 0x3FFFFull) != 0ull;
        } else {
            unsigned long long lowpart = W & ((1ull << l) - 1ull);   // bits t-l..t-1
            unsigned long long hipart  = Wm >> (46 + l);             // 18-l bits
            prev_any = (lowpart | hipart) != 0ull;
        }
        if (l <= 45) {
            next_any = ((W >> (l + 1)) & 0x3FFFFull) != 0ull;
        } else {
            unsigned long long a  = (l < 63) ? (W >> (l + 1)) : 0ull;     // 63-l bits
            unsigned long long bb = Wp & ((1ull << (l - 45)) - 1ull);      // l-45 bits
            next_any = (a | bb) != 0ull;
        }
        unsigned long long bS = __ballot(mt && !prev_any);
        unsigned long long bL = __ballot(mt && !next_any);
        if (lane == 0) { sw[wi] = bS; lw[wi] = bL; }
    }
    __syncthreads();

    // Phase 7: word-prefix counts of starts/lasts (wave 0)
    if (tid < NWORDS) {
        int cS = 0, cL = 0;
        for (int j = 0; j < tid; ++j) { cS += __popcll(sw[j]); cL += __popcll(lw[j]); }
        wbS[tid] = cS; wbL[tid] = cL;
        if (tid == NWORDS - 1) nseg_sh = cS + __popcll(sw[tid]);
    }
    __syncthreads();

    // Phase 8: scatter ordered start/last positions; clear S/E marker words
    for (int wi = wv; wi < NWORDS; wi += 4) {
        unsigned long long wS = sw[wi], wL = lw[wi];
        int t = (wi << 6) + lane;
        unsigned long long lmask = (1ull << lane) - 1ull;
        if ((wS >> lane) & 1ull) startpos[wbS[wi] + __popcll(wS & lmask)] = t;
        if ((wL >> lane) & 1ull) lastpos[wbL[wi] + __popcll(wL & lmask)] = t;
    }
    for (int wi = tid; wi < NWORDS; wi += 256) { Sw[wi] = 0ull; Ew[wi] = 0ull; }
    __syncthreads();

    // Phase 9: per segment: end = L (closed) or n (open, L >= n-18); validity; markers
    int nseg = nseg_sh;
    for (int k = tid; k < nseg; k += 256) {
        int s = startpos[k], L = lastpos[k];
        int e = (L >= NFRAMES - SILENCE_FRAMES) ? NFRAMES : L;
        if (e - s >= MIN_SPEECH_FRAMES) {
            atomicOr(&Sw[s >> 6], 1ull << (s & 63));
            atomicOr(&Ew[e >> 6], 1ull << (e & 63));
        }
    }
    __syncthreads();

    // Phase 10: word-prefix counts of S/E markers (reuse wbS/wbL)
    if (tid < NWORDS) {
        int cS = 0, cE = 0;
        for (int j = 0; j < tid; ++j) { cS += __popcll(Sw[j]); cE += __popcll(Ew[j]); }
        wbS[tid] = cS; wbL[tid] = cE;
    }
    __syncthreads();

    // Phase 11: coverage = (#starts <= t) > (#ends <= t); write int32 output
    int* orow = out + (size_t)b * NFRAMES;
    for (int wi = wv; wi < NWORDS; wi += 4) {
        unsigned long long wS2 = Sw[wi], wE2 = Ew[wi];
        int t = (wi << 6) + lane;
        unsigned long long ile = (lane == 63) ? ~0ull : ((1ull << (lane + 1)) - 1ull);
        int cS = wbS[wi] + __popcll(wS2 & ile);
        int cE = wbL[wi] + __popcll(wE2 & ile);
        if (t < NFRAMES) orow[t] = (cS > cE) ? 1 : 0;
    }
}

extern "C" void kernel_launch(void* const* d_in, const int* in_sizes, int n_in,
                              void* d_out, int out_size, void* d_ws, size_t ws_size,
                              hipStream_t stream) {
    const float* wav = (const float*)d_in[0];
    int* out = (int*)d_out;
    double* bs = (double*)d_ws;   // NBATCH*NBLOCKS doubles = 960 KB

    vad_block_sums<<<(NBATCH * NSAMP) / 4096, 256, 0, stream>>>(wav, bs);
    vad_finish<<<NBATCH, 256, 0, stream>>>(bs, out);
}

// Round 4
// 195.925 us; speedup vs baseline: 3.1546x; 1.0550x over previous
//
#include <hip/hip_runtime.h>

#define NFRAMES 3749   // (960000-512)/256 + 1
#define NBLOCKS 3750   // 256-sample hop blocks per batch (960000/256)
#define NSAMP   960000
#define NBATCH  32
#define NWORDS  59     // ceil(3750/64) -> covers bit index up to 3775 (incl. e==NFRAMES)
#define SILENCE_FRAMES 18
#define MIN_SPEECH_FRAMES 6
#define MAXSEG  256    // true bound: 1 + floor(3748/19) = 198

// Kernel A: fp64 sums of fp32 squares per 256-sample hop block. (unchanged, ~HBM-bound)
__global__ __launch_bounds__(256) void vad_block_sums(const float* __restrict__ wav,
                                                      double* __restrict__ bs) {
    int tid = threadIdx.x;
    const float* p = wav + (size_t)blockIdx.x * 4096 + tid * 16;
    double acc = 0.0;
    #pragma unroll
    for (int i = 0; i < 4; ++i) {
        float4 v = *(const float4*)(p + i * 4);
        acc += (double)(v.x * v.x);
        acc += (double)(v.y * v.y);
        acc += (double)(v.z * v.z);
        acc += (double)(v.w * v.w);
    }
    #pragma unroll
    for (int m = 1; m < 16; m <<= 1)
        acc += __shfl_xor(acc, m, 64);
    if ((tid & 15) == 0)
        bs[(size_t)blockIdx.x * 16 + (tid >> 4)] = acc;
}

// Kernel B: one block per batch. energies -> single radix-select + derive pass
// -> threshold -> mask bits -> parallel segment extraction -> int32 output.
__global__ __launch_bounds__(256) void vad_finish(const double* __restrict__ bs,
                                                  int* __restrict__ out) {
    __shared__ float eng[NFRAMES];
    __shared__ int hist4[4][256];               // per-wave histogram copies
    __shared__ unsigned long long mw[NWORDS];   // mask bits
    __shared__ unsigned long long sw[NWORDS];   // segment-start bits
    __shared__ unsigned long long lw[NWORDS];   // segment-last-one bits
    __shared__ unsigned long long Sw[NWORDS];   // valid-segment start markers
    __shared__ unsigned long long Ew[NWORDS];   // valid-segment end markers
    __shared__ int wbS[NWORDS], wbL[NWORDS];    // word-prefix bit counts
    __shared__ int startpos[MAXSEG], lastpos[MAXSEG];
    __shared__ int nzero_sh, nseg_sh;
    __shared__ unsigned sel_prefix_sh;
    __shared__ int sel_k_sh;
    __shared__ int cLE_sh;
    __shared__ unsigned minGT_sh;
    __shared__ float thr_sh;

    int b = blockIdx.x;
    int tid = threadIdx.x;
    int lane = tid & 63, wv = tid >> 6;
    const double* row = bs + (size_t)b * NBLOCKS;

    if (tid == 0) nzero_sh = 0;
    __syncthreads();

    // Phase 1: energies (exact fp64 sum -> single fp32 rounding), bits kept in
    // registers for the select passes; nzero counted on the fly.
    unsigned ub[15];
    int nel = 0, myzero = 0;
    #pragma unroll
    for (int i = 0; i < 15; ++i) {
        int t = tid + (i << 8);
        if (t < NFRAMES) {
            double s = row[t] + row[t + 1];
            float e = (float)(s * (1.0 / 512.0));
            eng[t] = e;
            ub[nel++] = __float_as_uint(e);
            if (e <= 0.0f) myzero++;
        }
    }
    if (myzero) atomicAdd(&nzero_sh, myzero);
    __syncthreads();

    int nzero = nzero_sh;
    int nz = NFRAMES - nzero;

    if (nz > 0) {   // block-uniform
        float pos = 0.2f * (float)(nz - 1);
        int lo = (int)floorf(pos), hi = (int)ceilf(pos);
        int rank_lo = min(max(nzero + lo, 0), NFRAMES - 1);
        int rank_hi = min(max(nzero + hi, 0), NFRAMES - 1);

        // Phase 2: radix select rank_lo (4 byte passes, MSB first).
        // Positive fp32 bit patterns order identically to the floats.
        for (int i = tid; i < 1024; i += 256) ((int*)hist4)[i] = 0;
        if (tid == 0) { sel_prefix_sh = 0u; sel_k_sh = rank_lo; }
        __syncthreads();

        for (int shift = 24; shift >= 0; shift -= 8) {
            unsigned pref = sel_prefix_sh;
            unsigned pmask = (shift == 24) ? 0u : (0xFFFFFFFFu << (shift + 8));
            for (int j = 0; j < nel; ++j) {
                unsigned u = ub[j];
                if ((u & pmask) == (pref & pmask))
                    atomicAdd(&hist4[wv][(u >> shift) & 255], 1);
            }
            __syncthreads();
            if (wv == 0) {
                int bin0 = lane << 2;
                int4 h0 = *(const int4*)&hist4[0][bin0];
                int4 h1 = *(const int4*)&hist4[1][bin0];
                int4 h2 = *(const int4*)&hist4[2][bin0];
                int4 h3 = *(const int4*)&hist4[3][bin0];
                int h[4];
                h[0] = h0.x + h1.x + h2.x + h3.x;
                h[1] = h0.y + h1.y + h2.y + h3.y;
                h[2] = h0.z + h1.z + h2.z + h3.z;
                h[3] = h0.w + h1.w + h2.w + h3.w;
                int tot = h[0] + h[1] + h[2] + h[3];
                int inc = tot;
                #pragma unroll
                for (int off = 1; off < 64; off <<= 1) {
                    int y = __shfl_up(inc, off, 64);
                    if (lane >= off) inc += y;
                }
                int run = inc - tot;                 // exclusive prefix of this lane's bins
                int k = sel_k_sh;
                #pragma unroll
                for (int j = 0; j < 4; ++j) {
                    if (k >= run && k < run + h[j]) { // exactly one (lane,j) hits
                        sel_prefix_sh = pref | ((unsigned)(bin0 + j) << shift);
                        sel_k_sh = k - run;
                    }
                    run += h[j];
                }
            }
            __syncthreads();
            if (shift > 0) {
                for (int i = tid; i < 1024; i += 256) ((int*)hist4)[i] = 0;
            }
            __syncthreads();
        }

        unsigned vb = sel_prefix_sh;   // bits of s[rank_lo]

        // Phase 3: derive s[rank_lo + 1] if needed (one reduce pass)
        if (rank_hi != rank_lo) {      // block-uniform
            if (tid == 0) { cLE_sh = 0; minGT_sh = 0xFFFFFFFFu; }
            __syncthreads();
            int c = 0;
            unsigned mg = 0xFFFFFFFFu;
            for (int j = 0; j < nel; ++j) {
                unsigned u = ub[j];
                if (u <= vb) c++;
                else mg = min(mg, u);
            }
            #pragma unroll
            for (int off = 32; off > 0; off >>= 1) {
                c += __shfl_xor(c, off, 64);
                mg = min(mg, (unsigned)__shfl_xor((int)mg, off, 64));
            }
            if (lane == 0) {
                atomicAdd(&cLE_sh, c);
                atomicMin(&minGT_sh, mg);
            }
            __syncthreads();
        }

        // Phase 4: threshold (fp32 arithmetic exactly as reference)
        if (tid == 0) {
            float vlo = __uint_as_float(vb);
            float vhi;
            if (rank_hi == rank_lo) vhi = vlo;
            else vhi = (cLE_sh >= rank_lo + 2) ? vlo : __uint_as_float(minGT_sh);
            float frac = pos - (float)lo;
            thr_sh = vlo * (1.0f - frac) + vhi * frac;
        }
    } else {
        if (tid == 0) thr_sh = 0.01f;
    }
    __syncthreads();
    float thr = thr_sh;

    // Phase 5: mask bit-words via ballot
    for (int wi = wv; wi < NWORDS; wi += 4) {
        int t = (wi << 6) + lane;
        bool p = (t < NFRAMES) && (eng[t] > thr);
        unsigned long long bm = __ballot(p);
        if (lane == 0) mw[wi] = bm;
    }
    __syncthreads();

    // Phase 6: segment starts (no 1 in prev 18) / last-ones (no 1 in next 18)
    for (int wi = wv; wi < NWORDS; wi += 4) {
        unsigned long long W  = mw[wi];
        unsigned long long Wm = (wi > 0) ? mw[wi - 1] : 0ull;
        unsigned long long Wp = (wi + 1 < NWORDS) ? mw[wi + 1] : 0ull;
        int l = lane;
        bool mt = (W >> l) & 1ull;
        bool prev_any, next_any;
        if (l >= 18) {
            prev_any = ((W >> (l - 18)) & 0x3FFFFull) != 0ull;
        } else {
            unsigned long long lowpart = W & ((1ull << l) - 1ull);   // bits t-l..t-1
            unsigned long long hipart  = Wm >> (46 + l);             // 18-l bits
            prev_any = (lowpart | hipart) != 0ull;
        }
        if (l <= 45) {
            next_any = ((W >> (l + 1)) & 0x3FFFFull) != 0ull;
        } else {
            unsigned long long a  = (l < 63) ? (W >> (l + 1)) : 0ull;     // 63-l bits
            unsigned long long bb = Wp & ((1ull << (l - 45)) - 1ull);      // l-45 bits
            next_any = (a | bb) != 0ull;
        }
        unsigned long long bS = __ballot(mt && !prev_any);
        unsigned long long bL = __ballot(mt && !next_any);
        if (lane == 0) { sw[wi] = bS; lw[wi] = bL; }
    }
    __syncthreads();

    // Phase 7: word-prefix counts of starts/lasts
    if (tid < NWORDS) {
        int cS = 0, cL = 0;
        for (int j = 0; j < tid; ++j) { cS += __popcll(sw[j]); cL += __popcll(lw[j]); }
        wbS[tid] = cS; wbL[tid] = cL;
        if (tid == NWORDS - 1) nseg_sh = cS + __popcll(sw[tid]);
    }
    __syncthreads();

    // Phase 8: scatter ordered start/last positions; clear S/E marker words
    for (int wi = wv; wi < NWORDS; wi += 4) {
        unsigned long long wS = sw[wi], wL = lw[wi];
        int t = (wi << 6) + lane;
        unsigned long long lmask = (1ull << lane) - 1ull;
        if ((wS >> lane) & 1ull) startpos[wbS[wi] + __popcll(wS & lmask)] = t;
        if ((wL >> lane) & 1ull) lastpos[wbL[wi] + __popcll(wL & lmask)] = t;
    }
    for (int wi = tid; wi < NWORDS; wi += 256) { Sw[wi] = 0ull; Ew[wi] = 0ull; }
    __syncthreads();

    // Phase 9: per segment: end = L (closed) or n (open, L >= n-18); validity; markers
    int nseg = nseg_sh;
    for (int k = tid; k < nseg; k += 256) {
        int s = startpos[k], L = lastpos[k];
        int e = (L >= NFRAMES - SILENCE_FRAMES) ? NFRAMES : L;
        if (e - s >= MIN_SPEECH_FRAMES) {
            atomicOr(&Sw[s >> 6], 1ull << (s & 63));
            atomicOr(&Ew[e >> 6], 1ull << (e & 63));
        }
    }
    __syncthreads();

    // Phase 10: word-prefix counts of S/E markers (reuse wbS/wbL)
    if (tid < NWORDS) {
        int cS = 0, cE = 0;
        for (int j = 0; j < tid; ++j) { cS += __popcll(Sw[j]); cE += __popcll(Ew[j]); }
        wbS[tid] = cS; wbL[tid] = cE;
    }
    __syncthreads();

    // Phase 11: coverage = (#starts <= t) > (#ends <= t); write int32 output
    int* orow = out + (size_t)b * NFRAMES;
    for (int wi = wv; wi < NWORDS; wi += 4) {
        unsigned long long wS2 = Sw[wi], wE2 = Ew[wi];
        int t = (wi << 6) + lane;
        unsigned long long ile = (lane == 63) ? ~0ull : ((1ull << (lane + 1)) - 1ull);
        int cS = wbS[wi] + __popcll(wS2 & ile);
        int cE = wbL[wi] + __popcll(wE2 & ile);
        if (t < NFRAMES) orow[t] = (cS > cE) ? 1 : 0;
    }
}

extern "C" void kernel_launch(void* const* d_in, const int* in_sizes, int n_in,
                              void* d_out, int out_size, void* d_ws, size_t ws_size,
                              hipStream_t stream) {
    const float* wav = (const float*)d_in[0];
    int* out = (int*)d_out;
    double* bs = (double*)d_ws;   // NBATCH*NBLOCKS doubles = 960 KB

    vad_block_sums<<<(NBATCH * NSAMP) / 4096, 256, 0, stream>>>(wav, bs);
    vad_finish<<<NBATCH, 256, 0, stream>>>(bs, out);
}